// Round 1
// baseline (10666.183 us; speedup 1.0000x reference)
//
#include <hip/hip_runtime.h>

// ComplexLSTM: B=32,S=512,I=512,H=512
// ws layout (bytes)
#define OFF_WZT   0ull
#define OFF_WHT   5242880ull
#define OFF_BIAS  10485760ull
#define OFF_XPERM 10496000ull
#define OFF_HBUF  94382080ull
#define OFF_CNT   94513152ull
#define NWG 64

typedef __attribute__((ext_vector_type(8))) short short8;
typedef __attribute__((ext_vector_type(4))) float f32x4;

__device__ __forceinline__ unsigned short f2bf(float f) {
  unsigned int u = __float_as_uint(f);
  u += 0x7fffu + ((u >> 16) & 1u);
  return (unsigned short)(u >> 16);
}
__device__ __forceinline__ float bf2f(unsigned short h) {
  return __uint_as_float(((unsigned int)h) << 16);
}

struct PackArgs {
  const float* zlo[5]; const float* zhi[5];
  const float* hlo[5]; const float* hhi[5];
  const float* bias[5];
};

// Pack: WzT/WhT[c][k]: c = g*512+h (g: 0=i,1=f,2=o,3=cr,4=ci), k<512 -> h_r coeff, k>=512 -> h_i coeff
__global__ void pack_kernel(PackArgs args, unsigned short* __restrict__ WzT,
                            unsigned short* __restrict__ WhT,
                            float* __restrict__ bias_out, int* __restrict__ cnt) {
  const long long total = 2ll * 2621440ll;
  long long stride = (long long)gridDim.x * blockDim.x;
  for (long long gid = (long long)blockIdx.x * blockDim.x + threadIdx.x; gid < total; gid += stride) {
    int sel = (int)(gid >= 2621440ll);
    int e = (int)(gid - (long long)sel * 2621440ll);
    int c = e >> 10, k = e & 1023;
    int g = c >> 9, h = c & 511;
    int kk = k & 511;
    const float* src = (k < 512) ? (sel ? args.hlo[g] : args.zlo[g])
                                 : (sel ? args.hhi[g] : args.zhi[g]);
    float sgn = (k < 512 || g == 4) ? 1.f : -1.f;
    float v = sgn * src[kk * 512 + h];
    (sel ? WhT : WzT)[(long long)c * 1024 + k] = f2bf(v);
  }
  int gid0 = blockIdx.x * blockDim.x + threadIdx.x;
  if (gid0 < 2560) { int g = gid0 >> 9; bias_out[gid0] = args.bias[g][gid0 & 511]; }
  if (gid0 < 512) cnt[gid0] = 0;
}

// Phase 1: X = [z_r|z_i](16384x1024) @ WzT^T + bias -> bf16, permuted to [t][wg][b][40]
__global__ __launch_bounds__(256) void phase1_kernel(
    const float* __restrict__ zr, const float* __restrict__ zi,
    const unsigned short* __restrict__ WzT, const float* __restrict__ bias,
    unsigned short* __restrict__ Xperm) {
  __shared__ unsigned short Al[64 * 40];
  __shared__ unsigned short Bl[64 * 40];
  int bid = blockIdx.x;
  int bm = bid / 40, bn = bid % 40;
  int tid = threadIdx.x;
  int wave = tid >> 6, lane = tid & 63;
  int mq = wave >> 1, nq = wave & 1;
  int lr = lane & 15, lkb = (lane >> 4) * 8;
  int srow = tid >> 2, sq = tid & 3;

  f32x4 acc[2][2];
#pragma unroll
  for (int i0 = 0; i0 < 2; i0++)
#pragma unroll
    for (int j0 = 0; j0 < 2; j0++) acc[i0][j0] = (f32x4){0.f, 0.f, 0.f, 0.f};

  for (int kb = 0; kb < 32; kb++) {
    int gk = kb * 32 + sq * 8;
    const float* srcp = (gk < 512) ? (zr + (long long)(bm * 64 + srow) * 512 + gk)
                                   : (zi + (long long)(bm * 64 + srow) * 512 + (gk - 512));
    float4 f0 = *(const float4*)srcp;
    float4 f1 = *(const float4*)(srcp + 4);
    uint4 p;
    p.x = (unsigned)f2bf(f0.x) | ((unsigned)f2bf(f0.y) << 16);
    p.y = (unsigned)f2bf(f0.z) | ((unsigned)f2bf(f0.w) << 16);
    p.z = (unsigned)f2bf(f1.x) | ((unsigned)f2bf(f1.y) << 16);
    p.w = (unsigned)f2bf(f1.z) | ((unsigned)f2bf(f1.w) << 16);
    *(uint4*)(&Al[srow * 40 + sq * 8]) = p;
    const unsigned short* bsrc = WzT + (long long)(bn * 64 + srow) * 1024 + kb * 32 + sq * 8;
    *(uint4*)(&Bl[srow * 40 + sq * 8]) = *(const uint4*)bsrc;
    __syncthreads();
    short8 a0 = *(const short8*)(&Al[(mq * 32 + 0 + lr) * 40 + lkb]);
    short8 a1 = *(const short8*)(&Al[(mq * 32 + 16 + lr) * 40 + lkb]);
    short8 b0 = *(const short8*)(&Bl[(nq * 32 + 0 + lr) * 40 + lkb]);
    short8 b1 = *(const short8*)(&Bl[(nq * 32 + 16 + lr) * 40 + lkb]);
    acc[0][0] = __builtin_amdgcn_mfma_f32_16x16x32_bf16(a0, b0, acc[0][0], 0, 0, 0);
    acc[0][1] = __builtin_amdgcn_mfma_f32_16x16x32_bf16(a0, b1, acc[0][1], 0, 0, 0);
    acc[1][0] = __builtin_amdgcn_mfma_f32_16x16x32_bf16(a1, b0, acc[1][0], 0, 0, 0);
    acc[1][1] = __builtin_amdgcn_mfma_f32_16x16x32_bf16(a1, b1, acc[1][1], 0, 0, 0);
    __syncthreads();
  }
#pragma unroll
  for (int mt = 0; mt < 2; mt++)
#pragma unroll
    for (int nt = 0; nt < 2; nt++) {
      int C = bn * 64 + nq * 32 + nt * 16 + lr;
      float bv = bias[C];
      int g = C >> 9, h = C & 511;
      int wgc = h >> 3, jj = h & 7;
#pragma unroll
      for (int r = 0; r < 4; r++) {
        int R = bm * 64 + mq * 32 + mt * 16 + (lane >> 4) * 4 + r;
        int bb = R >> 9, tt = R & 511;
        float v = acc[mt][nt][r] + bv;
        Xperm[(((long long)(tt * 64 + wgc)) * 32 + bb) * 40 + g * 8 + jj] = f2bf(v);
      }
    }
}

// Phase 2: persistent 64 WGs, WG w owns hidden cols [8w,8w+8) of all 5 gates.
__global__ __launch_bounds__(384) void recur_kernel(
    const unsigned short* __restrict__ WhT,
    const unsigned short* __restrict__ Xperm,
    unsigned short* __restrict__ Hbuf,
    int* __restrict__ cnt, float* __restrict__ out) {
  extern __shared__ unsigned short lds[];
  unsigned short* Wl = lds;                 // [40][1032] bf16
  unsigned short* Hl = lds + 40 * 1032;     // [32][1032] bf16
  float* gates = (float*)(lds + 40 * 1032); // overlay after MFMA: [6][16][16] f32

  int wg = blockIdx.x, tid = threadIdx.x;
  int wave = tid >> 6, lane = tid & 63;
  int m = (wave >= 3) ? 1 : 0;
  int n = wave - m * 3;
  int lr = lane & 15, lkb = (lane >> 4) * 8;

  // one-time: stage this WG's 40-column Wh slice into LDS
  for (int idx = tid; idx < 5120; idx += 384) {
    int r = idx >> 7, ch = idx & 127;
    int gcol = (r >> 3) * 512 + wg * 8 + (r & 7);
    uint4 v = *(const uint4*)(WhT + (long long)gcol * 1024 + ch * 8);
    *(uint4*)(&Wl[r * 1032 + ch * 8]) = v;
  }

  float c_r = 0.f, c_i = 0.f;
  int eb = tid >> 3, ej = tid & 7; // valid when tid < 256

  for (int t = 0; t < 512; t++) {
    float xg[5];
    if (tid < 256) {
      const unsigned short* xp = Xperm + (((long long)(t * 64 + wg)) * 32 + eb) * 40;
#pragma unroll
      for (int g = 0; g < 5; g++) xg[g] = bf2f(xp[g * 8 + ej]);
    }
    if (t == 0) {
      uint4 z = {0u, 0u, 0u, 0u};
      for (int idx = tid; idx < 4096; idx += 384) {
        int r = idx >> 7, ch = idx & 127;
        *(uint4*)(&Hl[r * 1032 + ch * 8]) = z;
      }
    } else {
      if (tid == 0) {
        while (__hip_atomic_load(cnt + (t - 1), __ATOMIC_ACQUIRE, __HIP_MEMORY_SCOPE_AGENT) < NWG) {
          __builtin_amdgcn_s_sleep(2);
        }
      }
      __syncthreads();
      __threadfence(); // acquire: invalidate stale L1/L2 before reading broadcast h
      const unsigned short* hb = Hbuf + ((t - 1) & 1) * 32768;
      for (int idx = tid; idx < 4096; idx += 384) {
        int r = idx >> 7, ch = idx & 127;
        *(uint4*)(&Hl[r * 1032 + ch * 8]) = *(const uint4*)(hb + r * 1024 + ch * 8);
      }
    }
    __syncthreads();

    f32x4 acc = {0.f, 0.f, 0.f, 0.f};
#pragma unroll 4
    for (int kk = 0; kk < 32; kk++) {
      short8 av = *(const short8*)(&Hl[(m * 16 + lr) * 1032 + kk * 32 + lkb]);
      short8 bv = *(const short8*)(&Wl[(n * 16 + lr) * 1032 + kk * 32 + lkb]);
      acc = __builtin_amdgcn_mfma_f32_16x16x32_bf16(av, bv, acc, 0, 0, 0);
    }
    __syncthreads(); // MFMA reads of Hl done before gates overlay write
    {
      int r0 = (lane >> 4) * 4;
#pragma unroll
      for (int r = 0; r < 4; r++) gates[wave * 256 + (r0 + r) * 16 + lr] = acc[r];
    }
    __syncthreads();

    if (tid < 256) {
      int mm = eb >> 4, br = eb & 15;
      float ip  = gates[(mm * 3 + 0) * 256 + br * 16 + ej]     + xg[0];
      float fp  = gates[(mm * 3 + 0) * 256 + br * 16 + 8 + ej] + xg[1];
      float op  = gates[(mm * 3 + 1) * 256 + br * 16 + ej]     + xg[2];
      float crp = gates[(mm * 3 + 1) * 256 + br * 16 + 8 + ej] + xg[3];
      float cip = gates[(mm * 3 + 2) * 256 + br * 16 + ej]     + xg[4];
      float ig = 1.f / (1.f + __expf(-ip));
      float fg = 1.f / (1.f + __expf(-fp));
      float og = 1.f / (1.f + __expf(-op));
      float mag = fmaxf(sqrtf(crp * crp + cip * cip + 1e-14f), 1e-8f);
      float e1 = __expf(-2.f * mag);
      float s1 = ((1.f - e1) / (1.f + e1)) / mag;
      c_r = fg * c_r + ig * (crp * s1);
      c_i = fg * c_i + ig * (cip * s1);
      float mag2 = fmaxf(sqrtf(c_r * c_r + c_i * c_i + 1e-14f), 1e-8f);
      float e2 = __expf(-2.f * mag2);
      float s2 = ((1.f - e2) / (1.f + e2)) / mag2;
      float hr = og * (c_r * s2);
      float hi = og * (c_i * s2);
      int j = wg * 8 + ej;
      out[(long long)eb * 262144 + t * 512 + j] = hr;
      out[8388608ll + (long long)eb * 262144 + t * 512 + j] = hi;
      unsigned short* hw = Hbuf + (t & 1) * 32768;
      hw[eb * 1024 + j] = f2bf(hr);
      hw[eb * 1024 + 512 + j] = f2bf(hi);
      if (t == 511) {
        out[16777216ll + eb * 512 + j] = hr;
        out[16793600ll + eb * 512 + j] = hi;
        out[16809984ll + eb * 512 + j] = c_r;
        out[16826368ll + eb * 512 + j] = c_i;
      }
    }
    __threadfence(); // release: h-broadcast writes visible device-wide
    __syncthreads();
    if (tid == 0)
      __hip_atomic_fetch_add(cnt + t, 1, __ATOMIC_RELEASE, __HIP_MEMORY_SCOPE_AGENT);
  }
}

extern "C" void kernel_launch(void* const* d_in, const int* in_sizes, int n_in,
                              void* d_out, int out_size, void* d_ws, size_t ws_size,
                              hipStream_t stream) {
  const float* zr = (const float*)d_in[0];
  const float* zi = (const float*)d_in[1];
  // input group bases: i=2, f=8, c=14, o=20; within: WzR,WzI,WhR,WhI,bR,bI
  const int gi = 2, gf = 8, gc = 14, go = 20;
  PackArgs pa;
  const int gbase[5] = {gi, gf, go, gc, gc}; // internal g: 0=i,1=f,2=o,3=cr,4=ci
  for (int g = 0; g < 5; g++) {
    int b = gbase[g];
    if (g < 4) {
      pa.zlo[g] = (const float*)d_in[b + 0];
      pa.zhi[g] = (const float*)d_in[b + 1];
      pa.hlo[g] = (const float*)d_in[b + 2];
      pa.hhi[g] = (const float*)d_in[b + 3];
    } else { // ci: k<512 uses imag weight (+), k>=512 uses real weight (+)
      pa.zlo[g] = (const float*)d_in[b + 1];
      pa.zhi[g] = (const float*)d_in[b + 0];
      pa.hlo[g] = (const float*)d_in[b + 3];
      pa.hhi[g] = (const float*)d_in[b + 2];
    }
  }
  pa.bias[0] = (const float*)d_in[gi + 4];
  pa.bias[1] = (const float*)d_in[gf + 4];
  pa.bias[2] = (const float*)d_in[go + 4];
  pa.bias[3] = (const float*)d_in[gc + 4];
  pa.bias[4] = (const float*)d_in[gc + 5];

  char* ws = (char*)d_ws;
  unsigned short* WzT = (unsigned short*)(ws + OFF_WZT);
  unsigned short* WhT = (unsigned short*)(ws + OFF_WHT);
  float* bias = (float*)(ws + OFF_BIAS);
  unsigned short* Xperm = (unsigned short*)(ws + OFF_XPERM);
  unsigned short* Hbuf = (unsigned short*)(ws + OFF_HBUF);
  int* cnt = (int*)(ws + OFF_CNT);

  pack_kernel<<<2048, 256, 0, stream>>>(pa, WzT, WhT, bias, cnt);
  phase1_kernel<<<10240, 256, 0, stream>>>(zr, zi, WzT, bias, Xperm);

  const int ldsBytes = 72 * 1032 * 2; // 148608
  hipFuncSetAttribute((const void*)recur_kernel,
                      hipFuncAttributeMaxDynamicSharedMemorySize, ldsBytes);
  recur_kernel<<<NWG, 384, ldsBytes, stream>>>(WhT, Xperm, Hbuf, cnt, (float*)d_out);
}

// Round 3
// 4652.820 us; speedup vs baseline: 2.2924x; 2.2924x over previous
//
#include <hip/hip_runtime.h>

// ComplexLSTM: B=32,S=512,I=512,H=512
// ws layout (bytes)
#define OFF_WZT   0ull
#define OFF_WHT   5242880ull
#define OFF_BIAS  10485760ull
#define OFF_XPERM 10496000ull
#define OFF_HBUF  94382080ull
#define OFF_CNT   94513152ull
#define NWG 64

typedef __attribute__((ext_vector_type(8))) short short8;
typedef __attribute__((ext_vector_type(4))) float f32x4;

__device__ __forceinline__ unsigned short f2bf(float f) {
  unsigned int u = __float_as_uint(f);
  u += 0x7fffu + ((u >> 16) & 1u);
  return (unsigned short)(u >> 16);
}
__device__ __forceinline__ float bf2f(unsigned short h) {
  return __uint_as_float(((unsigned int)h) << 16);
}

struct PackArgs {
  const float* zlo[5]; const float* zhi[5];
  const float* hlo[5]; const float* hhi[5];
  const float* bias[5];
};

// WzT[c][k]: k<512 -> z_r coeff (col k), k>=512 -> z_i coeff.
// WhT[c][k]: K interleaved: k=2*kk+ri, ri=0 -> h_r[kk] coeff, ri=1 -> h_i[kk] coeff.
// c = g*512+h (g: 0=i,1=f,2=o,3=cr,4=ci)
__global__ void pack_kernel(PackArgs args, unsigned short* __restrict__ WzT,
                            unsigned short* __restrict__ WhT,
                            float* __restrict__ bias_out, int* __restrict__ flag) {
  const long long total = 2ll * 2621440ll;
  long long stride = (long long)gridDim.x * blockDim.x;
  for (long long gid = (long long)blockIdx.x * blockDim.x + threadIdx.x; gid < total; gid += stride) {
    int sel = (int)(gid >= 2621440ll);
    int e = (int)(gid - (long long)sel * 2621440ll);
    int c = e >> 10, k = e & 1023;
    int g = c >> 9, h = c & 511;
    float v;
    if (sel) { // WhT interleaved
      int kk = k >> 1, ri = k & 1;
      const float* src = ri ? args.hhi[g] : args.hlo[g];
      float sgn = (!ri || g == 4) ? 1.f : -1.f;
      v = sgn * src[kk * 512 + h];
    } else {   // WzT block layout
      int kk = k & 511;
      const float* src = (k < 512) ? args.zlo[g] : args.zhi[g];
      float sgn = (k < 512 || g == 4) ? 1.f : -1.f;
      v = sgn * src[kk * 512 + h];
    }
    (sel ? WhT : WzT)[(long long)c * 1024 + k] = f2bf(v);
  }
  int gid0 = blockIdx.x * blockDim.x + threadIdx.x;
  if (gid0 < 2560) { int g = gid0 >> 9; bias_out[gid0] = args.bias[g][gid0 & 511]; }
  if (gid0 < 64) flag[gid0] = 0;
}

// Phase 1: X = [z_r|z_i](16384x1024) @ WzT^T + bias -> bf16, permuted to [t][wg][b][40]
__global__ __launch_bounds__(256) void phase1_kernel(
    const float* __restrict__ zr, const float* __restrict__ zi,
    const unsigned short* __restrict__ WzT, const float* __restrict__ bias,
    unsigned short* __restrict__ Xperm) {
  __shared__ unsigned short Al[64 * 40];
  __shared__ unsigned short Bl[64 * 40];
  int bid = blockIdx.x;
  int bm = bid / 40, bn = bid % 40;
  int tid = threadIdx.x;
  int wave = tid >> 6, lane = tid & 63;
  int mq = wave >> 1, nq = wave & 1;
  int lr = lane & 15, lkb = (lane >> 4) * 8;
  int srow = tid >> 2, sq = tid & 3;

  f32x4 acc[2][2];
#pragma unroll
  for (int i0 = 0; i0 < 2; i0++)
#pragma unroll
    for (int j0 = 0; j0 < 2; j0++) acc[i0][j0] = (f32x4){0.f, 0.f, 0.f, 0.f};

  for (int kb = 0; kb < 32; kb++) {
    int gk = kb * 32 + sq * 8;
    const float* srcp = (gk < 512) ? (zr + (long long)(bm * 64 + srow) * 512 + gk)
                                   : (zi + (long long)(bm * 64 + srow) * 512 + (gk - 512));
    float4 f0 = *(const float4*)srcp;
    float4 f1 = *(const float4*)(srcp + 4);
    uint4 p;
    p.x = (unsigned)f2bf(f0.x) | ((unsigned)f2bf(f0.y) << 16);
    p.y = (unsigned)f2bf(f0.z) | ((unsigned)f2bf(f0.w) << 16);
    p.z = (unsigned)f2bf(f1.x) | ((unsigned)f2bf(f1.y) << 16);
    p.w = (unsigned)f2bf(f1.z) | ((unsigned)f2bf(f1.w) << 16);
    *(uint4*)(&Al[srow * 40 + sq * 8]) = p;
    const unsigned short* bsrc = WzT + (long long)(bn * 64 + srow) * 1024 + kb * 32 + sq * 8;
    *(uint4*)(&Bl[srow * 40 + sq * 8]) = *(const uint4*)bsrc;
    __syncthreads();
    short8 a0 = *(const short8*)(&Al[(mq * 32 + 0 + lr) * 40 + lkb]);
    short8 a1 = *(const short8*)(&Al[(mq * 32 + 16 + lr) * 40 + lkb]);
    short8 b0 = *(const short8*)(&Bl[(nq * 32 + 0 + lr) * 40 + lkb]);
    short8 b1 = *(const short8*)(&Bl[(nq * 32 + 16 + lr) * 40 + lkb]);
    acc[0][0] = __builtin_amdgcn_mfma_f32_16x16x32_bf16(a0, b0, acc[0][0], 0, 0, 0);
    acc[0][1] = __builtin_amdgcn_mfma_f32_16x16x32_bf16(a0, b1, acc[0][1], 0, 0, 0);
    acc[1][0] = __builtin_amdgcn_mfma_f32_16x16x32_bf16(a1, b0, acc[1][0], 0, 0, 0);
    acc[1][1] = __builtin_amdgcn_mfma_f32_16x16x32_bf16(a1, b1, acc[1][1], 0, 0, 0);
    __syncthreads();
  }
#pragma unroll
  for (int mt = 0; mt < 2; mt++)
#pragma unroll
    for (int nt = 0; nt < 2; nt++) {
      int C = bn * 64 + nq * 32 + nt * 16 + lr;
      float bv = bias[C];
      int g = C >> 9, h = C & 511;
      int wgc = h >> 3, jj = h & 7;
#pragma unroll
      for (int r = 0; r < 4; r++) {
        int R = bm * 64 + mq * 32 + mt * 16 + (lane >> 4) * 4 + r;
        int bb = R >> 9, tt = R & 511;
        float v = acc[mt][nt][r] + bv;
        Xperm[(((long long)(tt * 64 + wgc)) * 32 + bb) * 40 + g * 8 + jj] = f2bf(v);
      }
    }
}

// Phase 2: persistent 64 WGs, WG w owns hidden cols [8w,8w+8) of all 5 gates.
// Hbuf32: [2][32][512] u32, word j = (bf16 h_r[j]) | (bf16 h_i[j] << 16)  (matches WhT interleaved K)
__global__ __launch_bounds__(384) void recur_kernel(
    const unsigned short* __restrict__ WhT,
    const unsigned short* __restrict__ Xperm,
    unsigned int* __restrict__ Hbuf32,
    int* __restrict__ flag, float* __restrict__ out) {
  extern __shared__ unsigned short lds[];
  unsigned short* Wl = lds;                 // [40][1032] bf16
  unsigned short* Hl = lds + 40 * 1032;     // [32][1032] bf16
  float* gates = (float*)(lds + 40 * 1032); // overlay after MFMA: [6][16][16] f32

  int wg = blockIdx.x, tid = threadIdx.x;
  int wave = tid >> 6, lane = tid & 63;
  int m = (wave >= 3) ? 1 : 0;
  int n = wave - m * 3;
  int lr = lane & 15, lkb = (lane >> 4) * 8;

  // one-time: stage this WG's 40-column Wh slice into LDS
  for (int idx = tid; idx < 5120; idx += 384) {
    int r = idx >> 7, ch = idx & 127;
    int gcol = (r >> 3) * 512 + wg * 8 + (r & 7);
    uint4 v = *(const uint4*)(WhT + (long long)gcol * 1024 + ch * 8);
    *(uint4*)(&Wl[r * 1032 + ch * 8]) = v;
  }

  float c_r = 0.f, c_i = 0.f;
  int eb = tid >> 3, ej = tid & 7; // valid when tid < 256

  for (int t = 0; t < 512; t++) {
    float xg[5];
    if (tid < 256) {
      const unsigned short* xp = Xperm + (((long long)(t * 64 + wg)) * 32 + eb) * 40;
#pragma unroll
      for (int g = 0; g < 5; g++) xg[g] = bf2f(xp[g * 8 + ej]);
    }
    if (t == 0) {
      uint4 z = {0u, 0u, 0u, 0u};
      for (int idx = tid; idx < 4096; idx += 384) {
        int r = idx >> 7, ch = idx & 127;
        *(uint4*)(&Hl[r * 1032 + ch * 8]) = z;
      }
    } else {
      // wait for all 64 WGs to have completed step t-1 (monotonic flags, relaxed polls)
      if (wave == 0) {
        while (true) {
          int v = __hip_atomic_load(flag + lane, __ATOMIC_RELAXED, __HIP_MEMORY_SCOPE_AGENT);
          if (__all(v >= t)) break;
          __builtin_amdgcn_s_sleep(1);
        }
      }
      __syncthreads();
      // single acquire fence (agent scope): invalidate stale lines, then plain vector loads
      __builtin_amdgcn_fence(__ATOMIC_ACQUIRE, "agent");
      const unsigned int* hb = Hbuf32 + ((t - 1) & 1) * 16384;
      for (int idx = tid; idx < 4096; idx += 384) {
        int r = idx >> 7, ch = idx & 127;
        *(uint4*)(&Hl[r * 1032 + ch * 8]) = *(const uint4*)(hb + r * 512 + ch * 4);
      }
    }
    __syncthreads();

    f32x4 acc = {0.f, 0.f, 0.f, 0.f};
#pragma unroll 4
    for (int kk = 0; kk < 32; kk++) {
      short8 av = *(const short8*)(&Hl[(m * 16 + lr) * 1032 + kk * 32 + lkb]);
      short8 bv = *(const short8*)(&Wl[(n * 16 + lr) * 1032 + kk * 32 + lkb]);
      acc = __builtin_amdgcn_mfma_f32_16x16x32_bf16(av, bv, acc, 0, 0, 0);
    }
    __syncthreads(); // MFMA reads of Hl done before gates overlay write
    {
      int r0 = (lane >> 4) * 4;
#pragma unroll
      for (int r = 0; r < 4; r++) gates[wave * 256 + (r0 + r) * 16 + lr] = acc[r];
    }
    __syncthreads();

    if (tid < 256) {
      int mm = eb >> 4, br = eb & 15;
      float ip  = gates[(mm * 3 + 0) * 256 + br * 16 + ej]     + xg[0];
      float fp  = gates[(mm * 3 + 0) * 256 + br * 16 + 8 + ej] + xg[1];
      float op  = gates[(mm * 3 + 1) * 256 + br * 16 + ej]     + xg[2];
      float crp = gates[(mm * 3 + 1) * 256 + br * 16 + 8 + ej] + xg[3];
      float cip = gates[(mm * 3 + 2) * 256 + br * 16 + ej]     + xg[4];
      float ig = 1.f / (1.f + __expf(-ip));
      float fg = 1.f / (1.f + __expf(-fp));
      float og = 1.f / (1.f + __expf(-op));
      float mag = fmaxf(sqrtf(crp * crp + cip * cip + 1e-14f), 1e-8f);
      float e1 = __expf(-2.f * mag);
      float s1 = ((1.f - e1) / (1.f + e1)) / mag;
      c_r = fg * c_r + ig * (crp * s1);
      c_i = fg * c_i + ig * (cip * s1);
      float mag2 = fmaxf(sqrtf(c_r * c_r + c_i * c_i + 1e-14f), 1e-8f);
      float e2 = __expf(-2.f * mag2);
      float s2 = ((1.f - e2) / (1.f + e2)) / mag2;
      float hr = og * (c_r * s2);
      float hi = og * (c_i * s2);
      int j = wg * 8 + ej;
      out[(long long)eb * 262144 + t * 512 + j] = hr;
      out[8388608ll + (long long)eb * 262144 + t * 512 + j] = hi;
      // h-broadcast: write-through store straight to the coherent point
      unsigned int hv = (unsigned)f2bf(hr) | ((unsigned)f2bf(hi) << 16);
      __hip_atomic_store(Hbuf32 + (t & 1) * 16384 + eb * 512 + j, hv,
                         __ATOMIC_RELAXED, __HIP_MEMORY_SCOPE_AGENT);
      if (t == 511) {
        out[16777216ll + eb * 512 + j] = hr;
        out[16793600ll + eb * 512 + j] = hi;
        out[16809984ll + eb * 512 + j] = c_r;
        out[16826368ll + eb * 512 + j] = c_i;
      }
    }
    // all h stores acked at the coherent point, then signal (no wbl2, no RMW contention)
    asm volatile("s_waitcnt vmcnt(0)" ::: "memory");
    __syncthreads();
    if (tid == 0)
      __hip_atomic_store(flag + wg, t + 1, __ATOMIC_RELAXED, __HIP_MEMORY_SCOPE_AGENT);
  }
}

extern "C" void kernel_launch(void* const* d_in, const int* in_sizes, int n_in,
                              void* d_out, int out_size, void* d_ws, size_t ws_size,
                              hipStream_t stream) {
  const float* zr = (const float*)d_in[0];
  const float* zi = (const float*)d_in[1];
  // input group bases: i=2, f=8, c=14, o=20; within: WzR,WzI,WhR,WhI,bR,bI
  const int gi = 2, gf = 8, gc = 14, go = 20;
  PackArgs pa;
  const int gbase[5] = {gi, gf, go, gc, gc}; // internal g: 0=i,1=f,2=o,3=cr,4=ci
  for (int g = 0; g < 5; g++) {
    int b = gbase[g];
    if (g < 4) {
      pa.zlo[g] = (const float*)d_in[b + 0];
      pa.zhi[g] = (const float*)d_in[b + 1];
      pa.hlo[g] = (const float*)d_in[b + 2];
      pa.hhi[g] = (const float*)d_in[b + 3];
    } else { // ci: "lo" (real-mult) uses imag weight (+), "hi" (imag-mult) uses real weight (+)
      pa.zlo[g] = (const float*)d_in[b + 1];
      pa.zhi[g] = (const float*)d_in[b + 0];
      pa.hlo[g] = (const float*)d_in[b + 3];
      pa.hhi[g] = (const float*)d_in[b + 2];
    }
  }
  pa.bias[0] = (const float*)d_in[gi + 4];
  pa.bias[1] = (const float*)d_in[gf + 4];
  pa.bias[2] = (const float*)d_in[go + 4];
  pa.bias[3] = (const float*)d_in[gc + 4];
  pa.bias[4] = (const float*)d_in[gc + 5];

  char* ws = (char*)d_ws;
  unsigned short* WzT = (unsigned short*)(ws + OFF_WZT);
  unsigned short* WhT = (unsigned short*)(ws + OFF_WHT);
  float* bias = (float*)(ws + OFF_BIAS);
  unsigned short* Xperm = (unsigned short*)(ws + OFF_XPERM);
  unsigned int* Hbuf32 = (unsigned int*)(ws + OFF_HBUF);
  int* flag = (int*)(ws + OFF_CNT);

  pack_kernel<<<2048, 256, 0, stream>>>(pa, WzT, WhT, bias, flag);
  phase1_kernel<<<10240, 256, 0, stream>>>(zr, zi, WzT, bias, Xperm);

  const int ldsBytes = 72 * 1032 * 2; // 148608
  (void)hipFuncSetAttribute((const void*)recur_kernel,
                            hipFuncAttributeMaxDynamicSharedMemorySize, ldsBytes);
  recur_kernel<<<NWG, 384, ldsBytes, stream>>>(WhT, Xperm, Hbuf32, flag, (float*)d_out);
}